// Round 2
// baseline (647.146 us; speedup 1.0000x reference)
//
#include <hip/hip_runtime.h>
#include <cstdint>
#include <cstddef>

#define TSEQ   2048
#define BATCH  2
#define BT     4096      // BATCH*TSEQ
#define DMODEL 1024
#define NHEADS 16
#define HDIM   64
#define FFDIM  4096

typedef __attribute__((ext_vector_type(8))) short short8;    // 8 bf16 = 4 VGPRs
typedef __attribute__((ext_vector_type(4))) float floatx4;   // MFMA acc

__device__ __forceinline__ float bf2f(unsigned short u) {
    union { unsigned int i; float f; } v; v.i = ((unsigned int)u) << 16; return v.f;
}
__device__ __forceinline__ unsigned short f2bf(float f) {
    union { float f; unsigned int i; } v; v.f = f;
    unsigned int r = v.i + 0x7fffu + ((v.i >> 16) & 1u);
    return (unsigned short)(r >> 16);
}

// ---------------- transpose + cast: in f32 [K][N] -> out bf16 [N][K] ----------------
__global__ void transpose_k(const float* __restrict__ in,
                            unsigned short* __restrict__ out, int K, int N) {
    __shared__ unsigned short tile[32][33];
    int nt = blockIdx.x * 32, kt = blockIdx.y * 32;
    int tx = threadIdx.x, ty = threadIdx.y; // (32,8)
    for (int i = 0; i < 4; ++i)
        tile[ty + 8 * i][tx] = f2bf(in[(size_t)(kt + ty + 8 * i) * N + nt + tx]);
    __syncthreads();
    for (int i = 0; i < 4; ++i)
        out[(size_t)(nt + ty + 8 * i) * K + kt + tx] = tile[tx][ty + 8 * i];
}

// ---------------- RMSNorm: f32 in -> bf16 out ----------------
__global__ void rmsnorm_k(const float* __restrict__ x,
                          const float* __restrict__ w,
                          unsigned short* __restrict__ out) {
    int row = blockIdx.x, t = threadIdx.x; // 256 threads, D=1024 -> 4 elems/thread
    float4 xv = *(const float4*)&x[(size_t)row * DMODEL + t * 4];
    float f[4] = {xv.x, xv.y, xv.z, xv.w};
    float ss = 0.f;
    for (int e = 0; e < 4; ++e) ss += f[e] * f[e];
    for (int m = 1; m < 64; m <<= 1) ss += __shfl_xor(ss, m);
    __shared__ float red[4];
    if ((t & 63) == 0) red[t >> 6] = ss;
    __syncthreads();
    float tot = red[0] + red[1] + red[2] + red[3];
    float sc = rsqrtf(tot * (1.f / DMODEL) + 1e-6f);
    float4 wv = *(const float4*)&w[t * 4];
    float wf[4] = {wv.x, wv.y, wv.z, wv.w};
    unsigned short ol[4];
    for (int e = 0; e < 4; ++e) ol[e] = f2bf(f[e] * sc * wf[e]);
    *(uint2*)&out[(size_t)row * DMODEL + t * 4] = *(uint2*)ol;
}

// ---------------- Residual + RMSNorm: out = rmsnorm(a+b) * w ----------------
// a,b are internal bf16; w is f32; out is bf16 (out_f32=0) or f32 (out_f32=1)
__global__ void resnorm_k(const unsigned short* __restrict__ a,
                          const unsigned short* __restrict__ b,
                          const float* __restrict__ w,
                          void* __restrict__ outp, int out_f32) {
    int row = blockIdx.x, t = threadIdx.x;
    unsigned short al[4], bl[4];
    *(uint2*)al = *(const uint2*)&a[(size_t)row * DMODEL + t * 4];
    *(uint2*)bl = *(const uint2*)&b[(size_t)row * DMODEL + t * 4];
    float f[4];
    float ss = 0.f;
    for (int e = 0; e < 4; ++e) { f[e] = bf2f(al[e]) + bf2f(bl[e]); ss += f[e] * f[e]; }
    for (int m = 1; m < 64; m <<= 1) ss += __shfl_xor(ss, m);
    __shared__ float red[4];
    if ((t & 63) == 0) red[t >> 6] = ss;
    __syncthreads();
    float tot = red[0] + red[1] + red[2] + red[3];
    float sc = rsqrtf(tot * (1.f / DMODEL) + 1e-6f);
    float4 wv = *(const float4*)&w[t * 4];
    float wf[4] = {wv.x, wv.y, wv.z, wv.w};
    if (out_f32) {
        float4 ov;
        ov.x = f[0] * sc * wf[0]; ov.y = f[1] * sc * wf[1];
        ov.z = f[2] * sc * wf[2]; ov.w = f[3] * sc * wf[3];
        *(float4*)&((float*)outp)[(size_t)row * DMODEL + t * 4] = ov;
    } else {
        unsigned short ol[4];
        for (int e = 0; e < 4; ++e) ol[e] = f2bf(f[e] * sc * wf[e]);
        *(uint2*)&((unsigned short*)outp)[(size_t)row * DMODEL + t * 4] = *(uint2*)ol;
    }
}

// ---------------- GEMM: C[M,N] = A[M,K] @ Bt[N,K]^T  (bf16 in/out, fp32 acc) ----------------
// 128x128 tile, BK=32, 4 waves, each wave 64x64 via 4x4 MFMA 16x16x32 frags.
__global__ __launch_bounds__(256) void gemm_bt_k(const unsigned short* __restrict__ A,
                                                 const unsigned short* __restrict__ Bt,
                                                 unsigned short* __restrict__ C,
                                                 int M, int N, int K, int do_silu) {
    __shared__ __align__(16) unsigned short As[128 * 40];
    __shared__ __align__(16) unsigned short Bs[128 * 40];
    int t = threadIdx.x;
    int bm = blockIdx.y * 128, bn = blockIdx.x * 128;
    int lane = t & 63, wave = t >> 6;
    int wm = (wave & 1) * 64, wn = (wave >> 1) * 64;
    int lr = lane & 15, lq = lane >> 4;
    floatx4 acc[4][4];
    for (int mi = 0; mi < 4; ++mi)
        for (int ni = 0; ni < 4; ++ni)
            acc[mi][ni] = (floatx4){0.f, 0.f, 0.f, 0.f};

    for (int k0 = 0; k0 < K; k0 += 32) {
        __syncthreads();
        for (int c = t; c < 512; c += 256) {
            int row = c >> 2, col = (c & 3) * 8;
            *(uint4*)&As[row * 40 + col] = *(const uint4*)&A[(size_t)(bm + row) * K + k0 + col];
            *(uint4*)&Bs[row * 40 + col] = *(const uint4*)&Bt[(size_t)(bn + row) * K + k0 + col];
        }
        __syncthreads();
        short8 a[4], b[4];
        for (int mi = 0; mi < 4; ++mi)
            a[mi] = *(const short8*)&As[(wm + mi * 16 + lr) * 40 + lq * 8];
        for (int ni = 0; ni < 4; ++ni)
            b[ni] = *(const short8*)&Bs[(wn + ni * 16 + lr) * 40 + lq * 8];
        for (int mi = 0; mi < 4; ++mi)
            for (int ni = 0; ni < 4; ++ni)
                acc[mi][ni] = __builtin_amdgcn_mfma_f32_16x16x32_bf16(a[mi], b[ni], acc[mi][ni], 0, 0, 0);
    }

    for (int mi = 0; mi < 4; ++mi)
        for (int ni = 0; ni < 4; ++ni)
            for (int r = 0; r < 4; ++r) {
                int m = bm + wm + mi * 16 + lq * 4 + r;
                int n = bn + wn + ni * 16 + lr;
                float v = acc[mi][ni][r];
                if (do_silu) v = v / (1.f + expf(-v));
                C[(size_t)m * N + n] = f2bf(v);
            }
}

// ---------------- Flash attention (causal), one block per (qtile64, b*h) ----------------
// q,k,v,o are [BT, DMODEL] bf16; head h occupies cols h*64..h*64+63.
__global__ __launch_bounds__(256) void attn_k(const unsigned short* __restrict__ q,
                                              const unsigned short* __restrict__ k,
                                              const unsigned short* __restrict__ v,
                                              unsigned short* __restrict__ o) {
    __shared__ __align__(16) unsigned short Ks[64 * 72];
    __shared__ __align__(16) unsigned short Vts[64 * 72];
    __shared__ __align__(16) unsigned short Ps[4 * 16 * 72];
    int qt = blockIdx.x, bh = blockIdx.y;
    int b = bh >> 4, h = bh & 15;
    size_t base = (size_t)b * TSEQ;
    int t = threadIdx.x, lane = t & 63, wave = t >> 6;
    int lr = lane & 15, lq = lane >> 4;

    // Q fragments (A operand layout: lane holds Q[row=lr][d=lq*8..lq*8+7])
    int qrow = qt * 64 + wave * 16 + lr;
    short8 qf0 = *(const short8*)&q[(base + qrow) * DMODEL + h * 64 + lq * 8];
    short8 qf1 = *(const short8*)&q[(base + qrow) * DMODEL + h * 64 + 32 + lq * 8];

    floatx4 oa[4];
    for (int nd = 0; nd < 4; ++nd) oa[nd] = (floatx4){0.f, 0.f, 0.f, 0.f};
    float mrow[4] = {-INFINITY, -INFINITY, -INFINITY, -INFINITY};
    float lrow[4] = {0.f, 0.f, 0.f, 0.f};

    for (int kt = 0; kt <= qt; ++kt) {
        __syncthreads();  // protect K/V LDS from prior-iter readers
        for (int c = t; c < 512; c += 256) {
            int row = c >> 3, d0 = (c & 7) * 8;
            *(uint4*)&Ks[row * 72 + d0] =
                *(const uint4*)&k[(base + kt * 64 + row) * DMODEL + h * 64 + d0];
            union { uint4 u4; unsigned short us[8]; } tv;
            tv.u4 = *(const uint4*)&v[(base + kt * 64 + row) * DMODEL + h * 64 + d0];
            for (int e = 0; e < 8; ++e) Vts[(d0 + e) * 72 + row] = tv.us[e];
        }
        __syncthreads();

        // S = Q K^T * scale, C-layout: S[row=lq*4+r][col=n*16+lr]
        floatx4 s[4];
        for (int n = 0; n < 4; ++n) {
            short8 kf0 = *(const short8*)&Ks[(n * 16 + lr) * 72 + lq * 8];
            short8 kf1 = *(const short8*)&Ks[(n * 16 + lr) * 72 + 32 + lq * 8];
            floatx4 z = (floatx4){0.f, 0.f, 0.f, 0.f};
            z = __builtin_amdgcn_mfma_f32_16x16x32_bf16(qf0, kf0, z, 0, 0, 0);
            s[n] = __builtin_amdgcn_mfma_f32_16x16x32_bf16(qf1, kf1, z, 0, 0, 0);
        }
        bool diag = (kt == qt);
        for (int n = 0; n < 4; ++n)
            for (int r = 0; r < 4; ++r) {
                float val = s[n][r] * 0.125f;
                if (diag) {
                    int qi = wave * 16 + lq * 4 + r;
                    int kj = n * 16 + lr;
                    if (kj > qi) val = -1e30f;
                }
                s[n][r] = val;
            }

        // online softmax (stats per row = lq*4+r, reduced across the 16 lanes of lr)
        float mnew[4], alpha[4], rs[4];
        for (int r = 0; r < 4; ++r) {
            float mt = fmaxf(fmaxf(s[0][r], s[1][r]), fmaxf(s[2][r], s[3][r]));
            for (int msk = 1; msk < 16; msk <<= 1) mt = fmaxf(mt, __shfl_xor(mt, msk));
            mnew[r] = fmaxf(mrow[r], mt);
            alpha[r] = expf(mrow[r] - mnew[r]);
            mrow[r] = mnew[r];
            rs[r] = 0.f;
        }
        for (int n = 0; n < 4; ++n)
            for (int r = 0; r < 4; ++r) {
                float p = expf(s[n][r] - mnew[r]);
                rs[r] += p;
                Ps[wave * 1152 + (lq * 4 + r) * 72 + n * 16 + lr] = f2bf(p);
            }
        for (int r = 0; r < 4; ++r) {
            for (int msk = 1; msk < 16; msk <<= 1) rs[r] += __shfl_xor(rs[r], msk);
            lrow[r] = lrow[r] * alpha[r] + rs[r];
        }
        for (int nd = 0; nd < 4; ++nd)
            for (int r = 0; r < 4; ++r) oa[nd][r] *= alpha[r];
        __syncthreads();  // P/Vt visible; waves in lockstep before PV

        // O += P V : A = P[m=i][k=j] from Ps, B = Vt[n=d][k=j]
        for (int kk = 0; kk < 2; ++kk) {
            short8 pf = *(const short8*)&Ps[wave * 1152 + lr * 72 + kk * 32 + lq * 8];
            for (int nd = 0; nd < 4; ++nd) {
                short8 vf = *(const short8*)&Vts[(nd * 16 + lr) * 72 + kk * 32 + lq * 8];
                oa[nd] = __builtin_amdgcn_mfma_f32_16x16x32_bf16(pf, vf, oa[nd], 0, 0, 0);
            }
        }
    }

    for (int nd = 0; nd < 4; ++nd)
        for (int r = 0; r < 4; ++r) {
            int tok = qt * 64 + wave * 16 + lq * 4 + r;
            float val = oa[nd][r] / lrow[r];
            o[(base + tok) * DMODEL + h * 64 + nd * 16 + lr] = f2bf(val);
        }
}

// ---------------- launch ----------------
extern "C" void kernel_launch(void* const* d_in, const int* in_sizes, int n_in,
                              void* d_out, int out_size, void* d_ws, size_t ws_size,
                              hipStream_t stream) {
    const float* x      = (const float*)d_in[0];
    const float* w_pre  = (const float*)d_in[1];
    const float* wq     = (const float*)d_in[2];
    const float* wk     = (const float*)d_in[3];
    const float* wv     = (const float*)d_in[4];
    const float* wo     = (const float*)d_in[5];
    const float* w_attn = (const float*)d_in[6];
    const float* w1     = (const float*)d_in[7];
    const float* w2     = (const float*)d_in[8];
    const float* w_ffn  = (const float*)d_in[9];

    char* ws = (char*)d_ws;
    const size_t MB = 1024 * 1024;
    unsigned short* hb   = (unsigned short*)(ws + 0);        // 8 MB [BT,D] bf16
    unsigned short* qb   = (unsigned short*)(ws + 8 * MB);   // 8 MB
    unsigned short* kb   = (unsigned short*)(ws + 16 * MB);  // 8 MB
    unsigned short* vb   = (unsigned short*)(ws + 24 * MB);  // 8 MB
    unsigned short* ab   = (unsigned short*)(ws + 32 * MB);  // 8 MB attn out
    unsigned short* ob   = (unsigned short*)(ws + 40 * MB);  // 8 MB o-proj out
    unsigned short* yb   = (unsigned short*)(ws + 48 * MB);  // 8 MB
    unsigned short* wqt  = (unsigned short*)(ws + 56 * MB);  // 2 MB bf16 [D,D]
    unsigned short* wkt  = (unsigned short*)(ws + 58 * MB);
    unsigned short* wvt  = (unsigned short*)(ws + 60 * MB);
    unsigned short* wot  = (unsigned short*)(ws + 62 * MB);
    unsigned short* w1t  = (unsigned short*)(ws + 64 * MB);  // 8 MB bf16 [FF,D]
    unsigned short* w2t  = (unsigned short*)(ws + 72 * MB);  // 8 MB bf16 [D,FF]
    unsigned short* midb = (unsigned short*)(ws + 8 * MB);   // 32 MB, reuses q/k/v/attn
    unsigned short* fb   = (unsigned short*)(ws + 0);        // 8 MB, reuses h

    dim3 tb(32, 8);
    transpose_k<<<dim3(DMODEL / 32, DMODEL / 32), tb, 0, stream>>>(wq, wqt, DMODEL, DMODEL);
    transpose_k<<<dim3(DMODEL / 32, DMODEL / 32), tb, 0, stream>>>(wk, wkt, DMODEL, DMODEL);
    transpose_k<<<dim3(DMODEL / 32, DMODEL / 32), tb, 0, stream>>>(wv, wvt, DMODEL, DMODEL);
    transpose_k<<<dim3(DMODEL / 32, DMODEL / 32), tb, 0, stream>>>(wo, wot, DMODEL, DMODEL);
    transpose_k<<<dim3(FFDIM / 32, DMODEL / 32), tb, 0, stream>>>(w1, w1t, DMODEL, FFDIM);
    transpose_k<<<dim3(DMODEL / 32, FFDIM / 32), tb, 0, stream>>>(w2, w2t, FFDIM, DMODEL);

    rmsnorm_k<<<BT, 256, 0, stream>>>(x, w_pre, hb);

    gemm_bt_k<<<dim3(DMODEL / 128, BT / 128), 256, 0, stream>>>(hb, wqt, qb, BT, DMODEL, DMODEL, 0);
    gemm_bt_k<<<dim3(DMODEL / 128, BT / 128), 256, 0, stream>>>(hb, wkt, kb, BT, DMODEL, DMODEL, 0);
    gemm_bt_k<<<dim3(DMODEL / 128, BT / 128), 256, 0, stream>>>(hb, wvt, vb, BT, DMODEL, DMODEL, 0);

    attn_k<<<dim3(TSEQ / 64, BATCH * NHEADS), 256, 0, stream>>>(qb, kb, vb, ab);

    gemm_bt_k<<<dim3(DMODEL / 128, BT / 128), 256, 0, stream>>>(ab, wot, ob, BT, DMODEL, DMODEL, 0);
    resnorm_k<<<BT, 256, 0, stream>>>(hb, ob, w_attn, yb, 0);

    gemm_bt_k<<<dim3(FFDIM / 128, BT / 128), 256, 0, stream>>>(yb, w1t, midb, BT, FFDIM, DMODEL, 1);
    gemm_bt_k<<<dim3(DMODEL / 128, BT / 128), 256, 0, stream>>>(midb, w2t, fb, BT, DMODEL, FFDIM, 0);
    resnorm_k<<<BT, 256, 0, stream>>>(yb, fb, w_ffn, d_out, 1);
}

// Round 3
// 499.709 us; speedup vs baseline: 1.2950x; 1.2950x over previous
//
#include <hip/hip_runtime.h>
#include <cstdint>
#include <cstddef>

#define TSEQ   2048
#define BATCH  2
#define BT     4096      // BATCH*TSEQ
#define DMODEL 1024
#define NHEADS 16
#define HDIM   64
#define FFDIM  4096

typedef __attribute__((ext_vector_type(8))) short short8;    // 8 bf16 = 4 VGPRs
typedef __attribute__((ext_vector_type(4))) float floatx4;   // MFMA acc

__device__ __forceinline__ float bf2f(unsigned short u) {
    union { unsigned int i; float f; } v; v.i = ((unsigned int)u) << 16; return v.f;
}
__device__ __forceinline__ unsigned short f2bf(float f) {
    union { float f; unsigned int i; } v; v.f = f;
    unsigned int r = v.i + 0x7fffu + ((v.i >> 16) & 1u);
    return (unsigned short)(r >> 16);
}

// async global->LDS, 16B per lane. LDS dest = wave-uniform base + lane*16.
__device__ __forceinline__ void gld_lds16(const unsigned short* g, unsigned short* l) {
    __builtin_amdgcn_global_load_lds(
        (const __attribute__((address_space(1))) uint32_t*)(const void*)g,
        (__attribute__((address_space(3))) uint32_t*)(void*)l, 16, 0, 0);
}

// ---------------- transpose + cast: in f32 [K][N] -> out bf16 [N][K] ----------------
__global__ void transpose_k(const float* __restrict__ in,
                            unsigned short* __restrict__ out, int K, int N) {
    __shared__ unsigned short tile[32][33];
    int nt = blockIdx.x * 32, kt = blockIdx.y * 32;
    int tx = threadIdx.x, ty = threadIdx.y; // (32,8)
    for (int i = 0; i < 4; ++i)
        tile[ty + 8 * i][tx] = f2bf(in[(size_t)(kt + ty + 8 * i) * N + nt + tx]);
    __syncthreads();
    for (int i = 0; i < 4; ++i)
        out[(size_t)(nt + ty + 8 * i) * K + kt + tx] = tile[tx][ty + 8 * i];
}

// ---------------- bf16 transpose: V [B*T][D] -> Vt [B*D][T] ----------------
__global__ void vtrans_k(const unsigned short* __restrict__ in,
                         unsigned short* __restrict__ out) {
    __shared__ unsigned short tile[32][33];
    int b = blockIdx.z;
    int ct = blockIdx.x * 32;   // D tile
    int rt = blockIdx.y * 32;   // T tile
    int tx = threadIdx.x, ty = threadIdx.y; // (32,8)
    for (int i = 0; i < 4; ++i)
        tile[ty + 8 * i][tx] = in[((size_t)b * TSEQ + rt + ty + 8 * i) * DMODEL + ct + tx];
    __syncthreads();
    for (int i = 0; i < 4; ++i)
        out[((size_t)b * DMODEL + ct + ty + 8 * i) * TSEQ + rt + tx] = tile[tx][ty + 8 * i];
}

// ---------------- RMSNorm: f32 in -> bf16 out ----------------
__global__ void rmsnorm_k(const float* __restrict__ x,
                          const float* __restrict__ w,
                          unsigned short* __restrict__ out) {
    int row = blockIdx.x, t = threadIdx.x; // 256 threads, D=1024 -> 4 elems/thread
    float4 xv = *(const float4*)&x[(size_t)row * DMODEL + t * 4];
    float f[4] = {xv.x, xv.y, xv.z, xv.w};
    float ss = 0.f;
    for (int e = 0; e < 4; ++e) ss += f[e] * f[e];
    for (int m = 1; m < 64; m <<= 1) ss += __shfl_xor(ss, m);
    __shared__ float red[4];
    if ((t & 63) == 0) red[t >> 6] = ss;
    __syncthreads();
    float tot = red[0] + red[1] + red[2] + red[3];
    float sc = rsqrtf(tot * (1.f / DMODEL) + 1e-6f);
    float4 wv = *(const float4*)&w[t * 4];
    float wf[4] = {wv.x, wv.y, wv.z, wv.w};
    unsigned short ol[4];
    for (int e = 0; e < 4; ++e) ol[e] = f2bf(f[e] * sc * wf[e]);
    *(uint2*)&out[(size_t)row * DMODEL + t * 4] = *(uint2*)ol;
}

// ---------------- Residual + RMSNorm: out = rmsnorm(a+b) * w ----------------
__global__ void resnorm_k(const unsigned short* __restrict__ a,
                          const unsigned short* __restrict__ b,
                          const float* __restrict__ w,
                          void* __restrict__ outp, int out_f32) {
    int row = blockIdx.x, t = threadIdx.x;
    unsigned short al[4], bl[4];
    *(uint2*)al = *(const uint2*)&a[(size_t)row * DMODEL + t * 4];
    *(uint2*)bl = *(const uint2*)&b[(size_t)row * DMODEL + t * 4];
    float f[4];
    float ss = 0.f;
    for (int e = 0; e < 4; ++e) { f[e] = bf2f(al[e]) + bf2f(bl[e]); ss += f[e] * f[e]; }
    for (int m = 1; m < 64; m <<= 1) ss += __shfl_xor(ss, m);
    __shared__ float red[4];
    if ((t & 63) == 0) red[t >> 6] = ss;
    __syncthreads();
    float tot = red[0] + red[1] + red[2] + red[3];
    float sc = rsqrtf(tot * (1.f / DMODEL) + 1e-6f);
    float4 wv = *(const float4*)&w[t * 4];
    float wf[4] = {wv.x, wv.y, wv.z, wv.w};
    if (out_f32) {
        float4 ov;
        ov.x = f[0] * sc * wf[0]; ov.y = f[1] * sc * wf[1];
        ov.z = f[2] * sc * wf[2]; ov.w = f[3] * sc * wf[3];
        *(float4*)&((float*)outp)[(size_t)row * DMODEL + t * 4] = ov;
    } else {
        unsigned short ol[4];
        for (int e = 0; e < 4; ++e) ol[e] = f2bf(f[e] * sc * wf[e]);
        *(uint2*)&((unsigned short*)outp)[(size_t)row * DMODEL + t * 4] = *(uint2*)ol;
    }
}

// ---------------- GEMM (m97 structure): C[M,N] = A[M,K] @ Bt[N,K]^T ----------------
// 128x128 tile, BK=32 unpadded LDS, global_load_lds width=16, 4 waves.
__global__ __launch_bounds__(256) void gemm_bt_k(const unsigned short* __restrict__ A,
                                                 const unsigned short* __restrict__ Bt,
                                                 unsigned short* __restrict__ C,
                                                 int M, int N, int K, int do_silu) {
    __shared__ __align__(16) unsigned short As[128 * 32];
    __shared__ __align__(16) unsigned short Bs[128 * 32];
    int t = threadIdx.x;
    int bm = blockIdx.y * 128, bn = blockIdx.x * 128;
    int lane = t & 63, wave = t >> 6;
    int wm = (wave & 1) * 64, wn = (wave >> 1) * 64;
    int lr = lane & 15, lq = lane >> 4;

    // staging: wave stages rows [wave*32, wave*32+32) of A-tile and B-tile.
    // each global_load_lds covers 16 rows (4 lanes x 16B per row).
    int srow = wave * 32 + (lane >> 2);
    int scol = (lane & 3) * 8;
    const unsigned short* gA0 = A + (size_t)(bm + srow) * K + scol;
    const unsigned short* gA1 = gA0 + (size_t)16 * K;
    const unsigned short* gB0 = Bt + (size_t)(bn + srow) * K + scol;
    const unsigned short* gB1 = gB0 + (size_t)16 * K;
    unsigned short* lA0 = &As[(wave * 32) * 32];
    unsigned short* lA1 = &As[(wave * 32 + 16) * 32];
    unsigned short* lB0 = &Bs[(wave * 32) * 32];
    unsigned short* lB1 = &Bs[(wave * 32 + 16) * 32];

    floatx4 acc[4][4];
    for (int mi = 0; mi < 4; ++mi)
        for (int ni = 0; ni < 4; ++ni)
            acc[mi][ni] = (floatx4){0.f, 0.f, 0.f, 0.f};

    for (int k0 = 0; k0 < K; k0 += 32) {
        gld_lds16(gA0 + k0, lA0);
        gld_lds16(gA1 + k0, lA1);
        gld_lds16(gB0 + k0, lB0);
        gld_lds16(gB1 + k0, lB1);
        __syncthreads();  // drains vmcnt -> staged data visible
        short8 a[4], b[4];
#pragma unroll
        for (int mi = 0; mi < 4; ++mi)
            a[mi] = *(const short8*)&As[(wm + mi * 16 + lr) * 32 + lq * 8];
#pragma unroll
        for (int ni = 0; ni < 4; ++ni)
            b[ni] = *(const short8*)&Bs[(wn + ni * 16 + lr) * 32 + lq * 8];
#pragma unroll
        for (int mi = 0; mi < 4; ++mi)
#pragma unroll
            for (int ni = 0; ni < 4; ++ni)
                acc[mi][ni] = __builtin_amdgcn_mfma_f32_16x16x32_bf16(a[mi], b[ni], acc[mi][ni], 0, 0, 0);
        __syncthreads();  // all waves done reading before next overwrite
    }

    for (int mi = 0; mi < 4; ++mi)
        for (int ni = 0; ni < 4; ++ni)
            for (int r = 0; r < 4; ++r) {
                int m = bm + wm + mi * 16 + lq * 4 + r;
                int n = bn + wn + ni * 16 + lr;
                float v = acc[mi][ni][r];
                if (do_silu) v = v / (1.f + __expf(-v));
                C[(size_t)m * N + n] = f2bf(v);
            }
}

// ---------------- Flash attention (causal), paired q-tiles ----------------
// q,k are [BT,DMODEL] bf16; vt is [B*DMODEL][TSEQ] bf16 (pre-transposed V).
// Block (p, bh): processes q-tiles qtA=p and qtB=31-p sharing one K/V pass.
__device__ __forceinline__ void flash_tile(
    const short8& qf0, const short8& qf1,
    floatx4* oa, float* mrow, float* lrw,
    const unsigned short* Ks, const unsigned short* Vts, unsigned short* Ps,
    int lr, int lq, int wave, bool diag)
{
    floatx4 s[4];
#pragma unroll
    for (int n = 0; n < 4; ++n) {
        short8 kf0 = *(const short8*)&Ks[(n * 16 + lr) * 72 + lq * 8];
        short8 kf1 = *(const short8*)&Ks[(n * 16 + lr) * 72 + 32 + lq * 8];
        floatx4 z = (floatx4){0.f, 0.f, 0.f, 0.f};
        z = __builtin_amdgcn_mfma_f32_16x16x32_bf16(qf0, kf0, z, 0, 0, 0);
        s[n] = __builtin_amdgcn_mfma_f32_16x16x32_bf16(qf1, kf1, z, 0, 0, 0);
    }
    const float SC = 0.18033688011112042f;  // (1/8) * log2(e): softmax in log2 domain
#pragma unroll
    for (int n = 0; n < 4; ++n)
#pragma unroll
        for (int r = 0; r < 4; ++r) {
            float val = s[n][r] * SC;
            if (diag && (n * 16 + lr) > (wave * 16 + lq * 4 + r)) val = -1e30f;
            s[n][r] = val;
        }
    float mnew[4], alpha[4], rs[4];
#pragma unroll
    for (int r = 0; r < 4; ++r) {
        float mt = fmaxf(fmaxf(s[0][r], s[1][r]), fmaxf(s[2][r], s[3][r]));
        for (int k = 1; k < 16; k <<= 1) mt = fmaxf(mt, __shfl_xor(mt, k));
        mnew[r] = fmaxf(mrow[r], mt);
        alpha[r] = exp2f(mrow[r] - mnew[r]);
        mrow[r] = mnew[r];
        rs[r] = 0.f;
    }
#pragma unroll
    for (int n = 0; n < 4; ++n)
#pragma unroll
        for (int r = 0; r < 4; ++r) {
            float pv = exp2f(s[n][r] - mnew[r]);
            rs[r] += pv;
            Ps[wave * 1152 + (lq * 4 + r) * 72 + n * 16 + lr] = f2bf(pv);
        }
#pragma unroll
    for (int r = 0; r < 4; ++r) {
        for (int k = 1; k < 16; k <<= 1) rs[r] += __shfl_xor(rs[r], k);
        lrw[r] = lrw[r] * alpha[r] + rs[r];
    }
#pragma unroll
    for (int nd = 0; nd < 4; ++nd)
#pragma unroll
        for (int r = 0; r < 4; ++r) oa[nd][r] *= alpha[r];
    // O += P V : A = P (own wave's strip, compiler orders same-wave LDS RAW), B = Vt rows
#pragma unroll
    for (int kx = 0; kx < 2; ++kx) {
        short8 pf = *(const short8*)&Ps[wave * 1152 + lr * 72 + kx * 32 + lq * 8];
#pragma unroll
        for (int nd = 0; nd < 4; ++nd) {
            short8 vf = *(const short8*)&Vts[(nd * 16 + lr) * 72 + kx * 32 + lq * 8];
            oa[nd] = __builtin_amdgcn_mfma_f32_16x16x32_bf16(pf, vf, oa[nd], 0, 0, 0);
        }
    }
}

__global__ __launch_bounds__(256) void attn_k(const unsigned short* __restrict__ q,
                                              const unsigned short* __restrict__ kg,
                                              const unsigned short* __restrict__ vt,
                                              unsigned short* __restrict__ o) {
    __shared__ __align__(16) unsigned short Ks[64 * 72];
    __shared__ __align__(16) unsigned short Vts[64 * 72];   // [dim][key]
    __shared__ __align__(16) unsigned short Ps[4 * 16 * 72];
    int p = blockIdx.x;              // 0..15
    int qtA = p, qtB = 31 - p;       // qtA < qtB, total compute = 33 tiles/block
    int bh = blockIdx.y;
    int b = bh >> 4, h = bh & 15;
    size_t base = (size_t)b * TSEQ;
    const unsigned short* vth = vt + ((size_t)b * DMODEL + h * 64) * TSEQ;
    int t = threadIdx.x, lane = t & 63, wave = t >> 6;
    int lr = lane & 15, lq = lane >> 4;

    int qrowA = qtA * 64 + wave * 16 + lr;
    int qrowB = qtB * 64 + wave * 16 + lr;
    short8 qA0 = *(const short8*)&q[(base + qrowA) * DMODEL + h * 64 + lq * 8];
    short8 qA1 = *(const short8*)&q[(base + qrowA) * DMODEL + h * 64 + 32 + lq * 8];
    short8 qB0 = *(const short8*)&q[(base + qrowB) * DMODEL + h * 64 + lq * 8];
    short8 qB1 = *(const short8*)&q[(base + qrowB) * DMODEL + h * 64 + 32 + lq * 8];

    floatx4 oA[4], oB[4];
    float mA[4], lA[4], mB[4], lB[4];
#pragma unroll
    for (int i = 0; i < 4; ++i) {
        oA[i] = (floatx4){0.f, 0.f, 0.f, 0.f};
        oB[i] = (floatx4){0.f, 0.f, 0.f, 0.f};
        mA[i] = -INFINITY; mB[i] = -INFINITY;
        lA[i] = 0.f; lB[i] = 0.f;
    }

    for (int kt = 0; kt <= qtB; ++kt) {
        __syncthreads();  // all waves done reading prev K/V tiles
        for (int c = t; c < 512; c += 256) {
            int row = c >> 3, d0 = (c & 7) * 8;
            *(uint4*)&Ks[row * 72 + d0] =
                *(const uint4*)&kg[(base + kt * 64 + row) * DMODEL + h * 64 + d0];
            *(uint4*)&Vts[row * 72 + d0] =
                *(const uint4*)&vth[(size_t)row * TSEQ + kt * 64 + d0];
        }
        __syncthreads();
        flash_tile(qB0, qB1, oB, mB, lB, Ks, Vts, Ps, lr, lq, wave, kt == qtB);
        if (kt <= qtA)
            flash_tile(qA0, qA1, oA, mA, lA, Ks, Vts, Ps, lr, lq, wave, kt == qtA);
    }

#pragma unroll
    for (int nd = 0; nd < 4; ++nd)
#pragma unroll
        for (int r = 0; r < 4; ++r) {
            int tokA = qtA * 64 + wave * 16 + lq * 4 + r;
            int tokB = qtB * 64 + wave * 16 + lq * 4 + r;
            o[(base + tokA) * DMODEL + h * 64 + nd * 16 + lr] = f2bf(oA[nd][r] / lA[r]);
            o[(base + tokB) * DMODEL + h * 64 + nd * 16 + lr] = f2bf(oB[nd][r] / lB[r]);
        }
}

// ---------------- launch ----------------
extern "C" void kernel_launch(void* const* d_in, const int* in_sizes, int n_in,
                              void* d_out, int out_size, void* d_ws, size_t ws_size,
                              hipStream_t stream) {
    const float* x      = (const float*)d_in[0];
    const float* w_pre  = (const float*)d_in[1];
    const float* wq     = (const float*)d_in[2];
    const float* wk     = (const float*)d_in[3];
    const float* wv     = (const float*)d_in[4];
    const float* wo     = (const float*)d_in[5];
    const float* w_attn = (const float*)d_in[6];
    const float* w1     = (const float*)d_in[7];
    const float* w2     = (const float*)d_in[8];
    const float* w_ffn  = (const float*)d_in[9];

    char* ws = (char*)d_ws;
    const size_t MB = 1024 * 1024;
    unsigned short* hb   = (unsigned short*)(ws + 0);        // 8 MB [BT,D] bf16
    unsigned short* qb   = (unsigned short*)(ws + 8 * MB);   // 8 MB
    unsigned short* kb   = (unsigned short*)(ws + 16 * MB);  // 8 MB
    unsigned short* vb   = (unsigned short*)(ws + 24 * MB);  // 8 MB
    unsigned short* ab   = (unsigned short*)(ws + 32 * MB);  // 8 MB attn out
    unsigned short* vtb  = (unsigned short*)(ws + 40 * MB);  // 8 MB V^T [B*D][T]; dead after attn
    unsigned short* ob   = (unsigned short*)(ws + 40 * MB);  // 8 MB o-proj out (after attn, aliases vtb)
    unsigned short* yb   = (unsigned short*)(ws + 48 * MB);  // 8 MB
    unsigned short* wqt  = (unsigned short*)(ws + 56 * MB);  // 2 MB bf16 [D,D]
    unsigned short* wkt  = (unsigned short*)(ws + 58 * MB);
    unsigned short* wvt  = (unsigned short*)(ws + 60 * MB);
    unsigned short* wot  = (unsigned short*)(ws + 62 * MB);
    unsigned short* w1t  = (unsigned short*)(ws + 64 * MB);  // 8 MB bf16 [FF,D]
    unsigned short* w2t  = (unsigned short*)(ws + 72 * MB);  // 8 MB bf16 [D,FF]
    unsigned short* midb = (unsigned short*)(ws + 8 * MB);   // 32 MB, reuses q/k/v/attn
    unsigned short* fb   = (unsigned short*)(ws + 0);        // 8 MB, reuses h

    dim3 tb(32, 8);
    transpose_k<<<dim3(DMODEL / 32, DMODEL / 32), tb, 0, stream>>>(wq, wqt, DMODEL, DMODEL);
    transpose_k<<<dim3(DMODEL / 32, DMODEL / 32), tb, 0, stream>>>(wk, wkt, DMODEL, DMODEL);
    transpose_k<<<dim3(DMODEL / 32, DMODEL / 32), tb, 0, stream>>>(wv, wvt, DMODEL, DMODEL);
    transpose_k<<<dim3(DMODEL / 32, DMODEL / 32), tb, 0, stream>>>(wo, wot, DMODEL, DMODEL);
    transpose_k<<<dim3(FFDIM / 32, DMODEL / 32), tb, 0, stream>>>(w1, w1t, DMODEL, FFDIM);
    transpose_k<<<dim3(DMODEL / 32, FFDIM / 32), tb, 0, stream>>>(w2, w2t, FFDIM, DMODEL);

    rmsnorm_k<<<BT, 256, 0, stream>>>(x, w_pre, hb);

    gemm_bt_k<<<dim3(DMODEL / 128, BT / 128), 256, 0, stream>>>(hb, wqt, qb, BT, DMODEL, DMODEL, 0);
    gemm_bt_k<<<dim3(DMODEL / 128, BT / 128), 256, 0, stream>>>(hb, wkt, kb, BT, DMODEL, DMODEL, 0);
    gemm_bt_k<<<dim3(DMODEL / 128, BT / 128), 256, 0, stream>>>(hb, wvt, vb, BT, DMODEL, DMODEL, 0);

    vtrans_k<<<dim3(DMODEL / 32, TSEQ / 32, BATCH), tb, 0, stream>>>(vb, vtb);

    attn_k<<<dim3(16, BATCH * NHEADS), 256, 0, stream>>>(qb, kb, vtb, ab);

    gemm_bt_k<<<dim3(DMODEL / 128, BT / 128), 256, 0, stream>>>(ab, wot, ob, BT, DMODEL, DMODEL, 0);
    resnorm_k<<<BT, 256, 0, stream>>>(hb, ob, w_attn, yb, 0);

    gemm_bt_k<<<dim3(FFDIM / 128, BT / 128), 256, 0, stream>>>(yb, w1t, midb, BT, FFDIM, DMODEL, 1);
    gemm_bt_k<<<dim3(DMODEL / 128, BT / 128), 256, 0, stream>>>(midb, w2t, fb, BT, DMODEL, FFDIM, 0);
    resnorm_k<<<BT, 256, 0, stream>>>(yb, fb, w_ffn, d_out, 1);
}

// Round 4
// 402.964 us; speedup vs baseline: 1.6060x; 1.2401x over previous
//
#include <hip/hip_runtime.h>
#include <cstdint>
#include <cstddef>

#define TSEQ   2048
#define BATCH  2
#define BT     4096      // BATCH*TSEQ
#define DMODEL 1024
#define NHEADS 16
#define HDIM   64
#define FFDIM  4096
#define QKVS   3072      // row stride of fused qkv buffer

typedef __attribute__((ext_vector_type(8))) short short8;    // 8 bf16 = 4 VGPRs
typedef __attribute__((ext_vector_type(4))) float floatx4;   // MFMA acc
typedef unsigned short us;

__device__ __forceinline__ float bf2f(us u) {
    union { unsigned int i; float f; } v; v.i = ((unsigned int)u) << 16; return v.f;
}
__device__ __forceinline__ us f2bf(float f) {
    union { float f; unsigned int i; } v; v.f = f;
    unsigned int r = v.i + 0x7fffu + ((v.i >> 16) & 1u);
    return (us)(r >> 16);
}

// async global->LDS, 16B per lane. LDS dest = wave-uniform base + lane*16.
__device__ __forceinline__ void gld_lds16(const us* g, us* l) {
    __builtin_amdgcn_global_load_lds(
        (const __attribute__((address_space(1))) uint32_t*)(const void*)g,
        (__attribute__((address_space(3))) uint32_t*)(void*)l, 16, 0, 0);
}

// ---------------- transpose + cast: in f32 [K][N] -> out bf16 [N][K] ----------------
__global__ void transpose_k(const float* __restrict__ in,
                            us* __restrict__ out, int K, int N) {
    __shared__ us tile[32][33];
    int nt = blockIdx.x * 32, kt = blockIdx.y * 32;
    int tx = threadIdx.x, ty = threadIdx.y; // (32,8)
    for (int i = 0; i < 4; ++i)
        tile[ty + 8 * i][tx] = f2bf(in[(size_t)(kt + ty + 8 * i) * N + nt + tx]);
    __syncthreads();
    for (int i = 0; i < 4; ++i)
        out[(size_t)(nt + ty + 8 * i) * K + kt + tx] = tile[tx][ty + 8 * i];
}

// ---------------- bf16 transpose: V (strided rows) -> Vt [B*D][T] ----------------
__global__ void vtrans_k(const us* __restrict__ in, us* __restrict__ out, int istride) {
    __shared__ us tile[32][33];
    int b = blockIdx.z;
    int ct = blockIdx.x * 32;   // D tile
    int rt = blockIdx.y * 32;   // T tile
    int tx = threadIdx.x, ty = threadIdx.y; // (32,8)
    for (int i = 0; i < 4; ++i)
        tile[ty + 8 * i][tx] = in[((size_t)b * TSEQ + rt + ty + 8 * i) * istride + ct + tx];
    __syncthreads();
    for (int i = 0; i < 4; ++i)
        out[((size_t)b * DMODEL + ct + ty + 8 * i) * TSEQ + rt + tx] = tile[tx][ty + 8 * i];
}

// ---------------- RMSNorm: f32 in -> bf16 out ----------------
__global__ void rmsnorm_k(const float* __restrict__ x,
                          const float* __restrict__ w,
                          us* __restrict__ out) {
    int row = blockIdx.x, t = threadIdx.x;
    float4 xv = *(const float4*)&x[(size_t)row * DMODEL + t * 4];
    float f[4] = {xv.x, xv.y, xv.z, xv.w};
    float ss = 0.f;
    for (int e = 0; e < 4; ++e) ss += f[e] * f[e];
    for (int m = 1; m < 64; m <<= 1) ss += __shfl_xor(ss, m);
    __shared__ float red[4];
    if ((t & 63) == 0) red[t >> 6] = ss;
    __syncthreads();
    float tot = red[0] + red[1] + red[2] + red[3];
    float sc = rsqrtf(tot * (1.f / DMODEL) + 1e-6f);
    float4 wv = *(const float4*)&w[t * 4];
    float wf[4] = {wv.x, wv.y, wv.z, wv.w};
    us ol[4];
    for (int e = 0; e < 4; ++e) ol[e] = f2bf(f[e] * sc * wf[e]);
    *(uint2*)&out[(size_t)row * DMODEL + t * 4] = *(uint2*)ol;
}

// ---------------- Residual + RMSNorm ----------------
__global__ void resnorm_k(const us* __restrict__ a, const us* __restrict__ b,
                          const float* __restrict__ w,
                          void* __restrict__ outp, int out_f32) {
    int row = blockIdx.x, t = threadIdx.x;
    us al[4], bl[4];
    *(uint2*)al = *(const uint2*)&a[(size_t)row * DMODEL + t * 4];
    *(uint2*)bl = *(const uint2*)&b[(size_t)row * DMODEL + t * 4];
    float f[4];
    float ss = 0.f;
    for (int e = 0; e < 4; ++e) { f[e] = bf2f(al[e]) + bf2f(bl[e]); ss += f[e] * f[e]; }
    for (int m = 1; m < 64; m <<= 1) ss += __shfl_xor(ss, m);
    __shared__ float red[4];
    if ((t & 63) == 0) red[t >> 6] = ss;
    __syncthreads();
    float tot = red[0] + red[1] + red[2] + red[3];
    float sc = rsqrtf(tot * (1.f / DMODEL) + 1e-6f);
    float4 wv = *(const float4*)&w[t * 4];
    float wf[4] = {wv.x, wv.y, wv.z, wv.w};
    if (out_f32) {
        float4 ov;
        ov.x = f[0] * sc * wf[0]; ov.y = f[1] * sc * wf[1];
        ov.z = f[2] * sc * wf[2]; ov.w = f[3] * sc * wf[3];
        *(float4*)&((float*)outp)[(size_t)row * DMODEL + t * 4] = ov;
    } else {
        us ol[4];
        for (int e = 0; e < 4; ++e) ol[e] = f2bf(f[e] * sc * wf[e]);
        *(uint2*)&((us*)outp)[(size_t)row * DMODEL + t * 4] = *(uint2*)ol;
    }
}

// ---------------- GEMM, double-buffered LDS, 1 barrier/iter ----------------
// C[M,N] = A[M,K] @ Bt[N,K]^T. Tile 128xBN, BK=32. BN=128: wave 64x64 (4x4 acc);
// BN=64: wave 64x32 (4x2 acc). Prefetch tile k+1 via global_load_lds right after
// the barrier admitting compute on tile k -> next barrier's vmcnt(0) drain waits
// on loads issued a full compute-phase earlier.
template<int BN>
__global__ __launch_bounds__(256) void gemm_dbuf_k(const us* __restrict__ A,
                                                   const us* __restrict__ Bt,
                                                   us* __restrict__ C,
                                                   int M, int N, int K, int do_silu) {
    constexpr int MI = 4, NI = (BN == 128 ? 4 : 2);
    __shared__ __align__(16) us As[2][128 * 32];
    __shared__ __align__(16) us Bs[2][BN * 32];
    int t = threadIdx.x;
    int bm = blockIdx.y * 128, bn = blockIdx.x * BN;
    int lane = t & 63, wave = t >> 6;
    int wm = (wave & 1) * 64, wn = (wave >> 1) * (BN / 2);
    int lr = lane & 15, lq = lane >> 4;

    // staging: lane covers (row = base + lane>>2, col = (lane&3)*8); 16 rows/instr
    int sr = lane >> 2, sc = (lane & 3) * 8;
    const us* gA = A + (size_t)(bm + wave * 32 + sr) * K + sc;
    const us* gB = Bt + (size_t)(bn + wave * (BN / 4) + sr) * K + sc;
    const int aoff = (wave * 32) * 32;
    const int boff = (wave * (BN / 4)) * 32;

    floatx4 acc[MI][NI];
#pragma unroll
    for (int mi = 0; mi < MI; ++mi)
#pragma unroll
        for (int ni = 0; ni < NI; ++ni)
            acc[mi][ni] = (floatx4){0.f, 0.f, 0.f, 0.f};

    // prologue: prefetch tile 0 into buf 0
    gld_lds16(gA, &As[0][aoff]);
    gld_lds16(gA + (size_t)16 * K, &As[0][aoff + 16 * 32]);
    gld_lds16(gB, &Bs[0][boff]);
    if (BN == 128) gld_lds16(gB + (size_t)16 * K, &Bs[0][boff + 16 * 32]);

    int nk = K >> 5;
    for (int kk = 0; kk < nk; ++kk) {
        __syncthreads();  // drains vmcnt: tile kk staged; closes reads of buf kk&1 from iter kk-2
        int cur = kk & 1, nxt = cur ^ 1;
        if (kk + 1 < nk) {
            size_t off = (size_t)(kk + 1) * 32;
            gld_lds16(gA + off, &As[nxt][aoff]);
            gld_lds16(gA + (size_t)16 * K + off, &As[nxt][aoff + 16 * 32]);
            gld_lds16(gB + off, &Bs[nxt][boff]);
            if (BN == 128) gld_lds16(gB + (size_t)16 * K + off, &Bs[nxt][boff + 16 * 32]);
        }
        short8 a[MI], b[NI];
#pragma unroll
        for (int mi = 0; mi < MI; ++mi)
            a[mi] = *(const short8*)&As[cur][(wm + mi * 16 + lr) * 32 + lq * 8];
#pragma unroll
        for (int ni = 0; ni < NI; ++ni)
            b[ni] = *(const short8*)&Bs[cur][(wn + ni * 16 + lr) * 32 + lq * 8];
#pragma unroll
        for (int mi = 0; mi < MI; ++mi)
#pragma unroll
            for (int ni = 0; ni < NI; ++ni)
                acc[mi][ni] = __builtin_amdgcn_mfma_f32_16x16x32_bf16(a[mi], b[ni], acc[mi][ni], 0, 0, 0);
    }

#pragma unroll
    for (int mi = 0; mi < MI; ++mi)
#pragma unroll
        for (int ni = 0; ni < NI; ++ni)
#pragma unroll
            for (int r = 0; r < 4; ++r) {
                int m = bm + wm + mi * 16 + lq * 4 + r;
                int n = bn + wn + ni * 16 + lr;
                float v = acc[mi][ni][r];
                if (do_silu) v = v / (1.f + __expf(-v));
                C[(size_t)m * N + n] = f2bf(v);
            }
}

// ---------------- Flash attention (causal), paired q-tiles, dbuf K/V ----------------
__device__ __forceinline__ void flash_tile(
    const short8& qf0, const short8& qf1,
    floatx4* oa, float* mrow, float* lrw,
    const us* Ks, const us* Vts, us* Ps,
    int lr, int lq, int wave, bool diag)
{
    floatx4 s[4];
#pragma unroll
    for (int n = 0; n < 4; ++n) {
        short8 kf0 = *(const short8*)&Ks[(n * 16 + lr) * 72 + lq * 8];
        short8 kf1 = *(const short8*)&Ks[(n * 16 + lr) * 72 + 32 + lq * 8];
        floatx4 z = (floatx4){0.f, 0.f, 0.f, 0.f};
        z = __builtin_amdgcn_mfma_f32_16x16x32_bf16(qf0, kf0, z, 0, 0, 0);
        s[n] = __builtin_amdgcn_mfma_f32_16x16x32_bf16(qf1, kf1, z, 0, 0, 0);
    }
    const float SC = 0.18033688011112042f;  // (1/8) * log2(e): softmax in log2 domain
#pragma unroll
    for (int n = 0; n < 4; ++n)
#pragma unroll
        for (int r = 0; r < 4; ++r) {
            float val = s[n][r] * SC;
            if (diag && (n * 16 + lr) > (wave * 16 + lq * 4 + r)) val = -1e30f;
            s[n][r] = val;
        }
    float mnew[4], alpha[4], rs[4];
#pragma unroll
    for (int r = 0; r < 4; ++r) {
        float mt = fmaxf(fmaxf(s[0][r], s[1][r]), fmaxf(s[2][r], s[3][r]));
        for (int k = 1; k < 16; k <<= 1) mt = fmaxf(mt, __shfl_xor(mt, k));
        mnew[r] = fmaxf(mrow[r], mt);
        alpha[r] = exp2f(mrow[r] - mnew[r]);
        mrow[r] = mnew[r];
        rs[r] = 0.f;
    }
#pragma unroll
    for (int n = 0; n < 4; ++n)
#pragma unroll
        for (int r = 0; r < 4; ++r) {
            float pv = exp2f(s[n][r] - mnew[r]);
            rs[r] += pv;
            Ps[wave * 1152 + (lq * 4 + r) * 72 + n * 16 + lr] = f2bf(pv);
        }
#pragma unroll
    for (int r = 0; r < 4; ++r) {
        for (int k = 1; k < 16; k <<= 1) rs[r] += __shfl_xor(rs[r], k);
        lrw[r] = lrw[r] * alpha[r] + rs[r];
    }
#pragma unroll
    for (int nd = 0; nd < 4; ++nd)
#pragma unroll
        for (int r = 0; r < 4; ++r) oa[nd][r] *= alpha[r];
#pragma unroll
    for (int kx = 0; kx < 2; ++kx) {
        short8 pf = *(const short8*)&Ps[wave * 1152 + lr * 72 + kx * 32 + lq * 8];
#pragma unroll
        for (int nd = 0; nd < 4; ++nd) {
            short8 vf = *(const short8*)&Vts[(nd * 16 + lr) * 72 + kx * 32 + lq * 8];
            oa[nd] = __builtin_amdgcn_mfma_f32_16x16x32_bf16(pf, vf, oa[nd], 0, 0, 0);
        }
    }
}

// q,kg are rows of the fused qkv buffer (row stride QKVS); vt is [B*D][T].
__global__ __launch_bounds__(256) void attn_k(const us* __restrict__ q,
                                              const us* __restrict__ kg,
                                              const us* __restrict__ vt,
                                              us* __restrict__ o) {
    __shared__ __align__(16) us Ks[2][64 * 72];
    __shared__ __align__(16) us Vts[2][64 * 72];   // [dim][key]
    __shared__ __align__(16) us Ps[4 * 16 * 72];
    int p = blockIdx.x;              // 0..15
    int qtA = p, qtB = 31 - p;       // 33 flash tiles per block (balanced)
    int bh = blockIdx.y;
    int b = bh >> 4, h = bh & 15;
    size_t base = (size_t)b * TSEQ;
    const us* vth = vt + ((size_t)b * DMODEL + h * 64) * TSEQ;
    int t = threadIdx.x, lane = t & 63, wave = t >> 6;
    int lr = lane & 15, lq = lane >> 4;

    int qrowA = qtA * 64 + wave * 16 + lr;
    int qrowB = qtB * 64 + wave * 16 + lr;
    short8 qA0 = *(const short8*)&q[(base + qrowA) * QKVS + h * 64 + lq * 8];
    short8 qA1 = *(const short8*)&q[(base + qrowA) * QKVS + h * 64 + 32 + lq * 8];
    short8 qB0 = *(const short8*)&q[(base + qrowB) * QKVS + h * 64 + lq * 8];
    short8 qB1 = *(const short8*)&q[(base + qrowB) * QKVS + h * 64 + 32 + lq * 8];

    floatx4 oA[4], oB[4];
    float mA[4], lA[4], mB[4], lB[4];
#pragma unroll
    for (int i = 0; i < 4; ++i) {
        oA[i] = (floatx4){0.f, 0.f, 0.f, 0.f};
        oB[i] = (floatx4){0.f, 0.f, 0.f, 0.f};
        mA[i] = -INFINITY; mB[i] = -INFINITY;
        lA[i] = 0.f; lB[i] = 0.f;
    }

    // staging: thread covers (row r0, cols d0..d0+7) and (row r0+32, same cols)
    int r0 = t >> 3, d0 = (t & 7) * 8;
    uint4 kr0, kr1, vr0, vr1;
    // prologue: load tile 0 into regs, write to buf 0
    kr0 = *(const uint4*)&kg[(base + r0) * QKVS + h * 64 + d0];
    kr1 = *(const uint4*)&kg[(base + r0 + 32) * QKVS + h * 64 + d0];
    vr0 = *(const uint4*)&vth[(size_t)r0 * TSEQ + d0];
    vr1 = *(const uint4*)&vth[(size_t)(r0 + 32) * TSEQ + d0];
    *(uint4*)&Ks[0][r0 * 72 + d0] = kr0;
    *(uint4*)&Ks[0][(r0 + 32) * 72 + d0] = kr1;
    *(uint4*)&Vts[0][r0 * 72 + d0] = vr0;
    *(uint4*)&Vts[0][(r0 + 32) * 72 + d0] = vr1;

    for (int kt = 0; kt <= qtB; ++kt) {
        __syncthreads();   // buf[cur] staged; prior readers of buf[nxt] done
        int cur = kt & 1, nxt = cur ^ 1;
        if (kt + 1 <= qtB) {   // issue next tile's global loads early
            kr0 = *(const uint4*)&kg[(base + (kt + 1) * 64 + r0) * QKVS + h * 64 + d0];
            kr1 = *(const uint4*)&kg[(base + (kt + 1) * 64 + r0 + 32) * QKVS + h * 64 + d0];
            vr0 = *(const uint4*)&vth[(size_t)r0 * TSEQ + (kt + 1) * 64 + d0];
            vr1 = *(const uint4*)&vth[(size_t)(r0 + 32) * TSEQ + (kt + 1) * 64 + d0];
        }
        flash_tile(qB0, qB1, oB, mB, lB, Ks[cur], Vts[cur], Ps, lr, lq, wave, kt == qtB);
        if (kt <= qtA)
            flash_tile(qA0, qA1, oA, mA, lA, Ks[cur], Vts[cur], Ps, lr, lq, wave, kt == qtA);
        if (kt + 1 <= qtB) {   // write-late: vmcnt waits hidden under compute
            *(uint4*)&Ks[nxt][r0 * 72 + d0] = kr0;
            *(uint4*)&Ks[nxt][(r0 + 32) * 72 + d0] = kr1;
            *(uint4*)&Vts[nxt][r0 * 72 + d0] = vr0;
            *(uint4*)&Vts[nxt][(r0 + 32) * 72 + d0] = vr1;
        }
    }

#pragma unroll
    for (int nd = 0; nd < 4; ++nd)
#pragma unroll
        for (int r = 0; r < 4; ++r) {
            int tokA = qtA * 64 + wave * 16 + lq * 4 + r;
            int tokB = qtB * 64 + wave * 16 + lq * 4 + r;
            o[(base + tokA) * DMODEL + h * 64 + nd * 16 + lr] = f2bf(oA[nd][r] / lA[r]);
            o[(base + tokB) * DMODEL + h * 64 + nd * 16 + lr] = f2bf(oB[nd][r] / lB[r]);
        }
}

// ---------------- launch ----------------
extern "C" void kernel_launch(void* const* d_in, const int* in_sizes, int n_in,
                              void* d_out, int out_size, void* d_ws, size_t ws_size,
                              hipStream_t stream) {
    const float* x      = (const float*)d_in[0];
    const float* w_pre  = (const float*)d_in[1];
    const float* wq     = (const float*)d_in[2];
    const float* wk     = (const float*)d_in[3];
    const float* wv     = (const float*)d_in[4];
    const float* wo     = (const float*)d_in[5];
    const float* w_attn = (const float*)d_in[6];
    const float* w1     = (const float*)d_in[7];
    const float* w2     = (const float*)d_in[8];
    const float* w_ffn  = (const float*)d_in[9];

    char* ws = (char*)d_ws;
    const size_t MB = 1024 * 1024;
    us* hb    = (us*)(ws + 0);        // 8 MB [BT,D] bf16
    us* qkvb  = (us*)(ws + 8 * MB);   // 24 MB [BT,3D] fused q|k|v
    us* ab    = (us*)(ws + 32 * MB);  // 8 MB attn out
    us* vtb   = (us*)(ws + 40 * MB);  // 8 MB V^T [B*D][T]; dead after attn
    us* ob    = (us*)(ws + 40 * MB);  // aliases vtb (o-proj out, written after attn)
    us* yb    = (us*)(ws + 48 * MB);  // 8 MB
    us* wqkvt = (us*)(ws + 56 * MB);  // 6 MB [3D][D] fused transposed weights
    us* wot   = (us*)(ws + 62 * MB);  // 2 MB
    us* w1t   = (us*)(ws + 64 * MB);  // 8 MB [FF][D]
    us* w2t   = (us*)(ws + 72 * MB);  // 8 MB [D][FF]
    us* midb  = (us*)(ws + 8 * MB);   // 32 MB (qkvb+ab dead by FFN time)
    us* fb    = (us*)(ws + 0);        // 8 MB reuses hb

    dim3 tb(32, 8);
    transpose_k<<<dim3(32, 32), tb, 0, stream>>>(wq, wqkvt, DMODEL, DMODEL);
    transpose_k<<<dim3(32, 32), tb, 0, stream>>>(wk, wqkvt + 1024 * 1024, DMODEL, DMODEL);
    transpose_k<<<dim3(32, 32), tb, 0, stream>>>(wv, wqkvt + 2 * 1024 * 1024, DMODEL, DMODEL);
    transpose_k<<<dim3(32, 32), tb, 0, stream>>>(wo, wot, DMODEL, DMODEL);
    transpose_k<<<dim3(FFDIM / 32, 32), tb, 0, stream>>>(w1, w1t, DMODEL, FFDIM);
    transpose_k<<<dim3(32, FFDIM / 32), tb, 0, stream>>>(w2, w2t, FFDIM, DMODEL);

    rmsnorm_k<<<BT, 256, 0, stream>>>(x, w_pre, hb);

    // fused QKV: [4096,1024] @ [3072,1024]^T -> [4096,3072]
    gemm_dbuf_k<128><<<dim3(QKVS / 128, BT / 128), 256, 0, stream>>>(
        hb, wqkvt, qkvb, BT, QKVS, DMODEL, 0);

    vtrans_k<<<dim3(DMODEL / 32, TSEQ / 32, BATCH), tb, 0, stream>>>(qkvb + 2048, vtb, QKVS);

    attn_k<<<dim3(16, BATCH * NHEADS), 256, 0, stream>>>(qkvb, qkvb + 1024, vtb, ab);

    gemm_dbuf_k<64><<<dim3(DMODEL / 64, BT / 128), 256, 0, stream>>>(
        ab, wot, ob, BT, DMODEL, DMODEL, 0);
    resnorm_k<<<BT, 256, 0, stream>>>(hb, ob, w_attn, yb, 0);

    gemm_dbuf_k<128><<<dim3(FFDIM / 128, BT / 128), 256, 0, stream>>>(
        yb, w1t, midb, BT, FFDIM, DMODEL, 1);
    gemm_dbuf_k<64><<<dim3(DMODEL / 64, BT / 128), 256, 0, stream>>>(
        midb, w2t, fb, BT, DMODEL, FFDIM, 0);
    resnorm_k<<<BT, 256, 0, stream>>>(yb, fb, w_ffn, d_out, 1);
}